// Round 5
// baseline (142.379 us; speedup 1.0000x reference)
//
#include <hip/hip_runtime.h>
#include <hip/hip_bf16.h>
#include <stdint.h>

// Problem: N=8192 tokens, D=128, HEADS=16, dh=2048.
// Pipeline: prep weights (fragment-major WT) -> q3/k3/v3 projections
//           (q3 pre-scaled by log2(e)/sqrt(D)) -> per-token attention
//           (DPP softmax, immediate-offset LDS partials) -> output projection.
//
// ws layout (~98 MB):
//   [0,32M)   q3  bf16 [n]{(h>>3)*1024 + i*8 + (h&7)}  (scaled by CEXP)
//             -- later overwritten by out3 [n][f]
//   [32,64M)  k3  bf16 same layout (unscaled)
//   [64,96M)  v3  bf16 [n]{(j>>3)*128 + h*8 + (j&7)}   (fragment units for PV)
//   [96M..)   WTq/WTk/WTv bf16 frag-major [g(64)][ks(8)][hi(2)][il(32)][8],
//             WoT bf16 [128 col][2048 k]

#define NTOK 8192
#define DDIM 128
#define DH   2048

typedef float   f32x16 __attribute__((ext_vector_type(16)));
typedef float   f32x4  __attribute__((ext_vector_type(4)));
typedef __bf16  bf16x8 __attribute__((ext_vector_type(8)));
typedef uint32_t u32x4 __attribute__((ext_vector_type(4)));

static __device__ __forceinline__ uint32_t cvt_pk_bf16(float lo, float hi) {
  uint32_t r;
  asm("v_cvt_pk_bf16_f32 %0, %1, %2" : "=v"(r) : "v"(lo), "v"(hi));
  return r;
}
static __device__ __forceinline__ float v_exp(float x) {
  float r;
  asm("v_exp_f32 %0, %1" : "=v"(r) : "v"(x));
  return r;
}
// C/D row mapping for mfma_f32_32x32x16: row = (r&3) + 8*(r>>2) + 4*hi, col = lane&31
static __device__ __forceinline__ int crow4(int r, int hi) {
  return (r & 3) + 8 * (r >> 2) + 4 * hi;
}
// Fusable DPP add step: s + dpp(s). GCNDPPCombine folds mov_dpp+add -> v_add_f32_dpp.
template <int CTRL>
static __device__ __forceinline__ float dpp_add(float s) {
  int t = __builtin_amdgcn_update_dpp(0, __builtin_bit_cast(int, s), CTRL, 0xf, 0xf, true);
  return s + __builtin_bit_cast(float, t);
}

// ---------------- Kernel 0: weight prep ----------------
// Wq/Wk/Wv f32 [128][2048] -> WT bf16 frag-major: [g=col>>5][ks][hi][il=col&31][8]
// Wo f32 [2048][128] -> WoT bf16 [128 col][2048 k]
__global__ __launch_bounds__(256) void prep_weights(
    const float* __restrict__ Wq, const float* __restrict__ Wk,
    const float* __restrict__ Wv, const float* __restrict__ Wo,
    uint16_t* __restrict__ WqT, uint16_t* __restrict__ WkT,
    uint16_t* __restrict__ WvT, uint16_t* __restrict__ WoT) {
  const int t = threadIdx.x, bx = blockIdx.x, z = blockIdx.y;
  if (z < 3) {
    const float* W = (z == 0) ? Wq : (z == 1) ? Wk : Wv;
    uint16_t* WT = (z == 0) ? WqT : (z == 1) ? WkT : WvT;
    const int col = bx * 256 + t;
    const int g = col >> 5, il = col & 31;
    for (int kc = 0; kc < 16; ++kc) {   // kc = k>>3 : ks = kc>>1, hi = kc&1
      u32x4 wv;
      #pragma unroll
      for (int p = 0; p < 4; ++p) {
        float f0 = W[(size_t)(kc * 8 + 2 * p) * DH + col];
        float f1 = W[(size_t)(kc * 8 + 2 * p + 1) * DH + col];
        wv[p] = cvt_pk_bf16(f0, f1);
      }
      *(u32x4*)(WT + (size_t)g * 4096 + (kc >> 1) * 512 + (kc & 1) * 256 + il * 8) = wv;
    }
  } else {
    const int col = t & 127, ksub = t >> 7;
    const int kbase = bx * 256 + ksub * 128;
    for (int kc = 0; kc < 16; ++kc) {
      const int k0 = kbase + kc * 8;
      u32x4 wv;
      #pragma unroll
      for (int p = 0; p < 4; ++p) {
        float f0 = Wo[(size_t)(k0 + 2 * p) * DDIM + col];
        float f1 = Wo[(size_t)(k0 + 2 * p + 1) * DDIM + col];
        wv[p] = cvt_pk_bf16(f0, f1);
      }
      *(u32x4*)(WoT + (size_t)col * DH + k0) = wv;
    }
  }
}

// ---------------- Kernel 1: Q/K/V projections ----------------
// C = A[8192x128] @ W[128x2048] + b, bf16 out in attention layouts.
// q3/k3 unit: idx = n*2048 + (h>>3)*1024 + i*8 + (h&7)        (f = i*16+h)
// v3   unit: idx = n*2048 + (j>>3)*128 + h*8 + (j&7)          (f = j*16+h)
// q3 is additionally scaled by CEXP = log2(e)/sqrt(128) (folded softmax scale).
__global__ __launch_bounds__(256, 3) void proj_kernel(
    const float* __restrict__ q, const float* __restrict__ kin,
    const float* __restrict__ v,
    const uint16_t* __restrict__ WqT, const uint16_t* __restrict__ WkT,
    const uint16_t* __restrict__ WvT,
    const float* __restrict__ bq, const float* __restrict__ bk,
    const float* __restrict__ bv,
    uint16_t* __restrict__ q3, uint16_t* __restrict__ k3,
    uint16_t* __restrict__ v3) {
  __shared__ uint16_t astage[4096];    // A tile, frag layout [ks][hi][il][8]
  __shared__ uint16_t tile[32 * 512];  // 32 KB destination-layout staging
  const int z = blockIdx.z;
  const float* A = (z == 0) ? q : (z == 1) ? kin : v;
  const uint16_t* WTf = (z == 0) ? WqT : (z == 1) ? WkT : WvT;
  const float* bias = (z == 0) ? bq : (z == 1) ? bk : bv;
  uint16_t* dst = (z == 0) ? q3 : (z == 1) ? k3 : v3;
  const bool vlayout = (z == 2);
  const float CEXP = 1.4426950408889634f * 0.08838834764831845f;
  const float cs = (z == 0) ? CEXP : 1.0f;

  const int t = threadIdx.x;
  const int w = t >> 6, l = t & 63;
  const int il = l & 31, hi = l >> 5;
  const int T = blockIdx.x, by = blockIdx.y;
  const int rowbase = T * 32;

  // ---- stage A tile (32x128 f32 -> bf16 frag layout), coalesced ----
  {
    const int rp = t >> 3, kc = t & 7;
    const float* ap = A + ((size_t)rowbase + rp) * DDIM + kc * 16;
    float4 f0 = *(const float4*)(ap + 0);
    float4 f1 = *(const float4*)(ap + 4);
    float4 f2 = *(const float4*)(ap + 8);
    float4 f3 = *(const float4*)(ap + 12);
    u32x4 u0 = { cvt_pk_bf16(f0.x, f0.y), cvt_pk_bf16(f0.z, f0.w),
                 cvt_pk_bf16(f1.x, f1.y), cvt_pk_bf16(f1.z, f1.w) };
    u32x4 u1 = { cvt_pk_bf16(f2.x, f2.y), cvt_pk_bf16(f2.z, f2.w),
                 cvt_pk_bf16(f3.x, f3.y), cvt_pk_bf16(f3.z, f3.w) };
    *(u32x4*)(astage + kc * 512 + rp * 8) = u0;        // hi=0 half
    *(u32x4*)(astage + kc * 512 + 256 + rp * 8) = u1;  // hi=1 half
  }
  __syncthreads();

  const int lo = hi * 256 + il * 8;
  bf16x8 af[8];
  #pragma unroll
  for (int ks = 0; ks < 8; ++ks)
    af[ks] = *(const bf16x8*)(astage + ks * 512 + lo);

  const uint16_t* WB = WTf + (size_t)(by * 16 + w * 4) * 4096;
  f32x16 acc0 = {}, acc1 = {}, acc2 = {}, acc3 = {};
  #pragma unroll
  for (int ks = 0; ks < 8; ++ks) {
    bf16x8 b0 = *(const bf16x8*)(WB + 0 * 4096 + ks * 512 + lo);
    bf16x8 b1 = *(const bf16x8*)(WB + 1 * 4096 + ks * 512 + lo);
    bf16x8 b2 = *(const bf16x8*)(WB + 2 * 4096 + ks * 512 + lo);
    bf16x8 b3 = *(const bf16x8*)(WB + 3 * 4096 + ks * 512 + lo);
    acc0 = __builtin_amdgcn_mfma_f32_32x32x16_bf16(af[ks], b0, acc0, 0, 0, 0);
    acc1 = __builtin_amdgcn_mfma_f32_32x32x16_bf16(af[ks], b1, acc1, 0, 0, 0);
    acc2 = __builtin_amdgcn_mfma_f32_32x32x16_bf16(af[ks], b2, acc2, 0, 0, 0);
    acc3 = __builtin_amdgcn_mfma_f32_32x32x16_bf16(af[ks], b3, acc3, 0, 0, 0);
  }

  // ---- stage into LDS in destination layout (local col lc) ----
  #pragma unroll
  for (int nt = 0; nt < 4; ++nt) {
    const f32x16 acc = (nt == 0) ? acc0 : (nt == 1) ? acc1 : (nt == 2) ? acc2 : acc3;
    const int lc = w * 128 + nt * 32 + il;
    const float bval = bias[by * 512 + lc];
    int cm;
    if (!vlayout) {
      const int c = (lc >> 3) & 1;
      cm = (c * 256 + (lc >> 4) * 8 + (lc & 7)) ^ (c << 4);
    } else {
      cm = ((lc >> 7) & 3) * 128 + (lc & 15) * 8 + ((lc >> 4) & 7);
    }
    #pragma unroll
    for (int r = 0; r < 16; r += 2) {
      const int rr0 = crow4(r, hi);              // r even: rr1 = rr0+1
      const uint32_t pk = cvt_pk_bf16((acc[r] + bval) * cs, (acc[r + 1] + bval) * cs);
      tile[rr0 * 512 + cm] = (uint16_t)pk;
      tile[(rr0 + 1) * 512 + cm] = (uint16_t)(pk >> 16);
    }
  }
  __syncthreads();

  // ---- coalesced store: 2048 16B-units, 8 per thread ----
  #pragma unroll
  for (int kk2 = 0; kk2 < 8; ++kk2) {
    const int u = t + kk2 * 256;
    const int rr = u >> 6, qq = u & 63;
    int toff;
    size_t gaddr;
    const size_t n = rowbase + rr;
    if (!vlayout) {
      toff = (qq * 8) ^ ((qq >> 5) << 4);   // undo stage swizzle
      gaddr = n * 2048 + (size_t)(qq >> 5) * 1024 + (size_t)by * 256 + (qq & 31) * 8;
    } else {
      toff = qq * 8;
      gaddr = n * 2048 + (size_t)by * 512 + (size_t)(qq >> 4) * 128 + (qq & 15) * 8;
    }
    u32x4 val = *(const u32x4*)(tile + rr * 512 + toff);
    *(u32x4*)(dst + gaddr) = val;
  }
}

// ---------------- Kernel 2: per-token attention ----------------
// One WG (4 waves) per token. S^T = k3 · q3^T; softmax over i via DPP row
// reduce + ds_swizzle xor16; P->bf16 via cvt_pk + permlane32_swap; PV per-mi;
// partials in LDS layout [w][i][h ^ c(i)], c(i)=((i&1)<<3)|((i>>1&1)<<2):
// writes are immediate-offset ds_write_b32 (2-way banks), epilogue reads are
// immediate-offset ds_read_b128 (conflict-free). out3 overwrites q3 region.
__global__ __launch_bounds__(256) void attn_kernel(
    const uint16_t* q3, const uint16_t* __restrict__ k3,
    const uint16_t* __restrict__ v3, uint16_t* out3) {
  __shared__ float part[4 * 2048];
  const int n = blockIdx.x;
  const int w = threadIdx.x >> 6;
  const int l = threadIdx.x & 63;
  const int il = l & 31, hi = l >> 5;
  const uint16_t* qb = q3 + (size_t)n * 2048;
  const uint16_t* kb = k3 + (size_t)n * 2048;
  const uint16_t* vb = v3 + (size_t)n * 2048;

  // A-frag: k3 rows j = 32w+il, k = h = hi*8..+7 ; V B-frags hoisted early.
  bf16x8 af = *(const bf16x8*)(kb + hi * 1024 + (size_t)(w * 32 + il) * 8);
  bf16x8 vf0 = *(const bf16x8*)(vb + (size_t)(w * 4 + hi) * 128 + (il & 15) * 8);
  bf16x8 vf1 = *(const bf16x8*)(vb + (size_t)(w * 4 + hi + 2) * 128 + (il & 15) * 8);
  f32x16 d0 = {}, d1 = {}, d2 = {}, d3 = {};
  {
    bf16x8 bq0 = *(const bf16x8*)(qb + hi * 1024 + (size_t)(0 * 32 + il) * 8);
    bf16x8 bq1 = *(const bf16x8*)(qb + hi * 1024 + (size_t)(1 * 32 + il) * 8);
    bf16x8 bq2 = *(const bf16x8*)(qb + hi * 1024 + (size_t)(2 * 32 + il) * 8);
    bf16x8 bq3 = *(const bf16x8*)(qb + hi * 1024 + (size_t)(3 * 32 + il) * 8);
    __builtin_amdgcn_s_setprio(1);
    d0 = __builtin_amdgcn_mfma_f32_32x32x16_bf16(af, bq0, d0, 0, 0, 0);
    d1 = __builtin_amdgcn_mfma_f32_32x32x16_bf16(af, bq1, d1, 0, 0, 0);
    d2 = __builtin_amdgcn_mfma_f32_32x32x16_bf16(af, bq2, d2, 0, 0, 0);
    d3 = __builtin_amdgcn_mfma_f32_32x32x16_bf16(af, bq3, d3, 0, 0, 0);
    __builtin_amdgcn_s_setprio(0);
  }
  // softmax over i (cols); scale folded into q3. Per row: sum 4 tiles +
  // DPP reduce (quad xor1, xor2, row_ror4, row_ror8) + ds_swizzle xor16.
  #pragma unroll
  for (int r = 0; r < 16; ++r) {
    float e0 = v_exp(d0[r]), e1 = v_exp(d1[r]);
    float e2 = v_exp(d2[r]), e3 = v_exp(d3[r]);
    float s = (e0 + e1) + (e2 + e3);
    s = dpp_add<0xB1>(s);    // quad_perm [1,0,3,2]  (xor 1)
    s = dpp_add<0x4E>(s);    // quad_perm [2,3,0,1]  (xor 2)
    s = dpp_add<0x124>(s);   // row_ror:4
    s = dpp_add<0x128>(s);   // row_ror:8  -> 16-lane row sum in all lanes
    s += __builtin_bit_cast(float,
           __builtin_amdgcn_ds_swizzle(__builtin_bit_cast(int, s), 0x401F));
    const float rs = __builtin_amdgcn_rcpf(s);
    d0[r] = e0 * rs; d1[r] = e1 * rs; d2[r] = e2 * rs; d3[r] = e3 * rs;
  }
  // Partial-write pointers: addr = w*2048 + i*16 + (h ^ c(i)), h = il (<16).
  // c depends only on r&3: r&3==0 -> 0, 1 -> 8, 2 -> 4, 3 -> 12.
  const int b0 = w * 2048 + hi * 64 + il;    // i's 4*hi gives +64 words
  float* pw0 = part + b0;
  float* pw8 = part + (b0 ^ 8);
  float* pw4 = part + (b0 ^ 4);
  float* pwC = part + (b0 ^ 12);
  // PV per i-tile: pack P^T -> A-frags, 2 MFMA, immediate-offset partial write.
  #pragma unroll
  for (int mi = 0; mi < 4; ++mi) {
    const f32x16 p = (mi == 0) ? d0 : (mi == 1) ? d1 : (mi == 2) ? d2 : d3;
    uint32_t pk0 = cvt_pk_bf16(p[0],  p[1]),  pk1 = cvt_pk_bf16(p[2],  p[3]);
    uint32_t pk2 = cvt_pk_bf16(p[4],  p[5]),  pk3 = cvt_pk_bf16(p[6],  p[7]);
    uint32_t pk4 = cvt_pk_bf16(p[8],  p[9]),  pk5 = cvt_pk_bf16(p[10], p[11]);
    uint32_t pk6 = cvt_pk_bf16(p[12], p[13]), pk7 = cvt_pk_bf16(p[14], p[15]);
    // swap(x,y): r[0] = [x_lo | y_lo], r[1] = [x_hi | y_hi]
    auto sA = __builtin_amdgcn_permlane32_swap(pk0, pk2, false, false); // W0, W2
    auto sB = __builtin_amdgcn_permlane32_swap(pk1, pk3, false, false); // W1, W3
    auto sC = __builtin_amdgcn_permlane32_swap(pk4, pk6, false, false); // W0',W2'
    auto sD = __builtin_amdgcn_permlane32_swap(pk5, pk7, false, false); // W1',W3'
    u32x4 fw0 = { sA[0], sB[0], sA[1], sB[1] };
    u32x4 fw1 = { sC[0], sD[0], sC[1], sD[1] };
    f32x16 oz = {};
    __builtin_amdgcn_s_setprio(1);
    oz = __builtin_amdgcn_mfma_f32_32x32x16_bf16(__builtin_bit_cast(bf16x8, fw0), vf0, oz, 0, 0, 0);
    oz = __builtin_amdgcn_mfma_f32_32x32x16_bf16(__builtin_bit_cast(bf16x8, fw1), vf1, oz, 0, 0, 0);
    __builtin_amdgcn_s_setprio(0);
    if (il < 16) {
      #pragma unroll
      for (int r = 0; r < 16; ++r) {
        float* pp = ((r & 3) == 0) ? pw0 : ((r & 3) == 1) ? pw8
                  : ((r & 3) == 2) ? pw4 : pwC;
        pp[mi * 512 + (r & 3) * 16 + (r >> 2) * 128] = oz[r];
      }
    }
  }
  __syncthreads();
  // Epilogue: thread t -> (i0 = t>>1, h = h0..h0+7), 8 x ds_read_b128.
  const int t = threadIdx.x;
  const int i0 = t >> 1, h0 = (t & 1) * 8;
  const int c0 = ((i0 & 1) << 3) | (((i0 >> 1) & 1) << 2);
  const int offa = i0 * 16 + (h0 ^ (c0 & 8)) + (c0 & 4);
  const int offb = i0 * 16 + (h0 ^ (c0 & 8)) + (4 ^ (c0 & 4));
  f32x4 a0 = *(const f32x4*)(part + offa);
  f32x4 b0v = *(const f32x4*)(part + offb);
  f32x4 a1 = *(const f32x4*)(part + 2048 + offa);
  f32x4 b1v = *(const f32x4*)(part + 2048 + offb);
  f32x4 a2 = *(const f32x4*)(part + 4096 + offa);
  f32x4 b2v = *(const f32x4*)(part + 4096 + offb);
  f32x4 a3 = *(const f32x4*)(part + 6144 + offa);
  f32x4 b3v = *(const f32x4*)(part + 6144 + offb);
  f32x4 sa = (a0 + a1) + (a2 + a3);     // h0..h0+3
  f32x4 sb = (b0v + b1v) + (b2v + b3v); // h0+4..h0+7
  u32x4 ov = { cvt_pk_bf16(sa[0], sa[1]), cvt_pk_bf16(sa[2], sa[3]),
               cvt_pk_bf16(sb[0], sb[1]), cvt_pk_bf16(sb[2], sb[3]) };
  *(u32x4*)(out3 + (size_t)n * 2048 + t * 8) = ov;
}

// ---------------- Kernel 3: output projection ----------------
// out = out3[8192x2048](bf16) @ Wo + bo, f32 out. K-split 2 per block.
__global__ __launch_bounds__(512) void outproj_kernel(
    const uint16_t* __restrict__ out3, const uint16_t* __restrict__ WoT,
    const float* __restrict__ bo, float* __restrict__ out) {
  __shared__ float part[4][32][32];
  const int w = threadIdx.x >> 6;
  const int l = threadIdx.x & 63;
  const int il = l & 31, hi = l >> 5;
  const int nt = w >> 1, ksv = w & 1;
  const int rowbase = blockIdx.x * 32;
  f32x16 acc = {};
  #pragma unroll 4
  for (int kb = 0; kb < 64; ++kb) {
    const int kk = ksv * 1024 + kb * 16 + hi * 8;
    bf16x8 afr = *(const bf16x8*)(out3 + (size_t)(rowbase + il) * DH + kk);
    bf16x8 bfr = *(const bf16x8*)(WoT + (size_t)(nt * 32 + il) * DH + kk);
    acc = __builtin_amdgcn_mfma_f32_32x32x16_bf16(afr, bfr, acc, 0, 0, 0);
  }
  if (ksv == 1) {
    #pragma unroll
    for (int r = 0; r < 16; ++r) part[nt][crow4(r, hi)][il] = acc[r];
  }
  __syncthreads();
  if (ksv == 0) {
    const int col = nt * 32 + il;
    const float bval = bo[col];
    #pragma unroll
    for (int r = 0; r < 16; ++r) {
      const int rr = crow4(r, hi);
      out[(size_t)(rowbase + rr) * DDIM + col] = acc[r] + part[nt][rr][il] + bval;
    }
  }
}

extern "C" void kernel_launch(void* const* d_in, const int* in_sizes, int n_in,
                              void* d_out, int out_size, void* d_ws, size_t ws_size,
                              hipStream_t stream) {
  (void)in_sizes; (void)n_in; (void)out_size; (void)ws_size;
  const float* q  = (const float*)d_in[0];
  const float* k  = (const float*)d_in[1];
  const float* v  = (const float*)d_in[2];
  const float* Wq = (const float*)d_in[3];
  const float* bq = (const float*)d_in[4];
  const float* Wk = (const float*)d_in[5];
  const float* bk = (const float*)d_in[6];
  const float* Wv = (const float*)d_in[7];
  const float* bv = (const float*)d_in[8];
  const float* Wo = (const float*)d_in[9];
  const float* bo = (const float*)d_in[10];
  float* out = (float*)d_out;

  char* ws = (char*)d_ws;
  const size_t MB = 1024ull * 1024ull;
  uint16_t* q3  = (uint16_t*)(ws);             // 32MB; becomes out3
  uint16_t* k3  = (uint16_t*)(ws + 32 * MB);
  uint16_t* v3  = (uint16_t*)(ws + 64 * MB);
  uint16_t* WqT = (uint16_t*)(ws + 96 * MB);   // 512KB each
  uint16_t* WkT = WqT + (size_t)DH * 128;
  uint16_t* WvT = WkT + (size_t)DH * 128;
  uint16_t* WoT = WvT + (size_t)DH * 128;

  prep_weights<<<dim3(8, 4), 256, 0, stream>>>(Wq, Wk, Wv, Wo, WqT, WkT, WvT, WoT);
  proj_kernel<<<dim3(256, 4, 3), 256, 0, stream>>>(q, k, v, WqT, WkT, WvT,
                                                   bq, bk, bv, q3, k3, v3);
  attn_kernel<<<dim3(NTOK), 256, 0, stream>>>(q3, k3, v3, q3);
  outproj_kernel<<<dim3(256), 512, 0, stream>>>(q3, WoT, bo, out);
}

// Round 7
// 121.168 us; speedup vs baseline: 1.1751x; 1.1751x over previous
//
#include <hip/hip_runtime.h>
#include <hip/hip_bf16.h>
#include <stdint.h>

// Problem: N=8192 tokens, D=128, HEADS=16, dh=2048.
// Pipeline: prep weights (fragment-major WT) -> q3/k3/v3 projections
//           (q3 pre-scaled by log2(e)/sqrt(D)) -> per-token attention
//           (strip softmax + P-fragment LDS exchange + O^T=V*P) -> outproj.
//
// ws layout (~98 MB):
//   [0,32M)   q3  bf16 [n]{(h>>3)*1024 + i*8 + (h&7)}  (scaled by CEXP)
//             -- later overwritten by out3 [n][f]
//   [32,64M)  k3  bf16 same layout (unscaled)
//   [64,96M)  v3  bf16 [n]{(j>>3)*128 + h*8 + (j&7)}   (fragment units for PV)
//   [96M..)   WTq/WTk/WTv bf16 frag-major [g(64)][ks(8)][hi(2)][il(32)][8],
//             WoT bf16 [128 col][2048 k]

#define NTOK 8192
#define DDIM 128
#define DH   2048

typedef float    f32x16 __attribute__((ext_vector_type(16)));
typedef float    f32x4  __attribute__((ext_vector_type(4)));
typedef __bf16   bf16x8 __attribute__((ext_vector_type(8)));
typedef uint32_t u32x4  __attribute__((ext_vector_type(4)));
typedef uint32_t u32x2  __attribute__((ext_vector_type(2)));

static __device__ __forceinline__ uint32_t cvt_pk_bf16(float lo, float hi) {
  uint32_t r;
  asm("v_cvt_pk_bf16_f32 %0, %1, %2" : "=v"(r) : "v"(lo), "v"(hi));
  return r;
}
static __device__ __forceinline__ float v_exp(float x) {
  float r;
  asm("v_exp_f32 %0, %1" : "=v"(r) : "v"(x));
  return r;
}
// C/D row mapping for mfma_f32_32x32x16: row = (r&3) + 8*(r>>2) + 4*hi, col = lane&31
static __device__ __forceinline__ int crow4(int r, int hi) {
  return (r & 3) + 8 * (r >> 2) + 4 * hi;
}
// Fusable DPP add step: s + dpp(s). GCNDPPCombine folds mov_dpp+add -> v_add_f32_dpp.
template <int CTRL>
static __device__ __forceinline__ float dpp_add(float s) {
  int t = __builtin_amdgcn_update_dpp(0, __builtin_bit_cast(int, s), CTRL, 0xf, 0xf, true);
  return s + __builtin_bit_cast(float, t);
}

// ---------------- Kernel 0: weight prep ----------------
// Wq/Wk/Wv f32 [128][2048] -> WT bf16 frag-major: [g=col>>5][ks][hi][il=col&31][8]
// Wo f32 [2048][128] -> WoT bf16 [128 col][2048 k]
__global__ __launch_bounds__(256) void prep_weights(
    const float* __restrict__ Wq, const float* __restrict__ Wk,
    const float* __restrict__ Wv, const float* __restrict__ Wo,
    uint16_t* __restrict__ WqT, uint16_t* __restrict__ WkT,
    uint16_t* __restrict__ WvT, uint16_t* __restrict__ WoT) {
  const int t = threadIdx.x, bx = blockIdx.x, z = blockIdx.y;
  if (z < 3) {
    const float* W = (z == 0) ? Wq : (z == 1) ? Wk : Wv;
    uint16_t* WT = (z == 0) ? WqT : (z == 1) ? WkT : WvT;
    const int col = bx * 256 + t;
    const int g = col >> 5, il = col & 31;
    for (int kc = 0; kc < 16; ++kc) {   // kc = k>>3 : ks = kc>>1, hi = kc&1
      u32x4 wv;
      #pragma unroll
      for (int p = 0; p < 4; ++p) {
        float f0 = W[(size_t)(kc * 8 + 2 * p) * DH + col];
        float f1 = W[(size_t)(kc * 8 + 2 * p + 1) * DH + col];
        wv[p] = cvt_pk_bf16(f0, f1);
      }
      *(u32x4*)(WT + (size_t)g * 4096 + (kc >> 1) * 512 + (kc & 1) * 256 + il * 8) = wv;
    }
  } else {
    const int col = t & 127, ksub = t >> 7;
    const int kbase = bx * 256 + ksub * 128;
    for (int kc = 0; kc < 16; ++kc) {
      const int k0 = kbase + kc * 8;
      u32x4 wv;
      #pragma unroll
      for (int p = 0; p < 4; ++p) {
        float f0 = Wo[(size_t)(k0 + 2 * p) * DDIM + col];
        float f1 = Wo[(size_t)(k0 + 2 * p + 1) * DDIM + col];
        wv[p] = cvt_pk_bf16(f0, f1);
      }
      *(u32x4*)(WoT + (size_t)col * DH + k0) = wv;
    }
  }
}

// ---------------- Kernel 1: Q/K/V projections ----------------
// C = A[8192x128] @ W[128x2048] + b, bf16 out in attention layouts.
// q3/k3 unit: idx = n*2048 + (h>>3)*1024 + i*8 + (h&7)        (f = i*16+h)
// v3   unit: idx = n*2048 + (j>>3)*128 + h*8 + (j&7)          (f = j*16+h)
// q3 is additionally scaled by CEXP = log2(e)/sqrt(128) (folded softmax scale).
__global__ __launch_bounds__(256, 3) void proj_kernel(
    const float* __restrict__ q, const float* __restrict__ kin,
    const float* __restrict__ v,
    const uint16_t* __restrict__ WqT, const uint16_t* __restrict__ WkT,
    const uint16_t* __restrict__ WvT,
    const float* __restrict__ bq, const float* __restrict__ bk,
    const float* __restrict__ bv,
    uint16_t* __restrict__ q3, uint16_t* __restrict__ k3,
    uint16_t* __restrict__ v3) {
  __shared__ uint16_t astage[4096];    // A tile, frag layout [ks][hi][il][8]
  __shared__ uint16_t tile[32 * 512];  // 32 KB destination-layout staging
  const int z = blockIdx.z;
  const float* A = (z == 0) ? q : (z == 1) ? kin : v;
  const uint16_t* WTf = (z == 0) ? WqT : (z == 1) ? WkT : WvT;
  const float* bias = (z == 0) ? bq : (z == 1) ? bk : bv;
  uint16_t* dst = (z == 0) ? q3 : (z == 1) ? k3 : v3;
  const bool vlayout = (z == 2);
  const float CEXP = 1.4426950408889634f * 0.08838834764831845f;
  const float cs = (z == 0) ? CEXP : 1.0f;

  const int t = threadIdx.x;
  const int w = t >> 6, l = t & 63;
  const int il = l & 31, hi = l >> 5;
  const int T = blockIdx.x, by = blockIdx.y;
  const int rowbase = T * 32;

  // ---- stage A tile (32x128 f32 -> bf16 frag layout), coalesced ----
  {
    const int rp = t >> 3, kc = t & 7;
    const float* ap = A + ((size_t)rowbase + rp) * DDIM + kc * 16;
    float4 f0 = *(const float4*)(ap + 0);
    float4 f1 = *(const float4*)(ap + 4);
    float4 f2 = *(const float4*)(ap + 8);
    float4 f3 = *(const float4*)(ap + 12);
    u32x4 u0 = { cvt_pk_bf16(f0.x, f0.y), cvt_pk_bf16(f0.z, f0.w),
                 cvt_pk_bf16(f1.x, f1.y), cvt_pk_bf16(f1.z, f1.w) };
    u32x4 u1 = { cvt_pk_bf16(f2.x, f2.y), cvt_pk_bf16(f2.z, f2.w),
                 cvt_pk_bf16(f3.x, f3.y), cvt_pk_bf16(f3.z, f3.w) };
    *(u32x4*)(astage + kc * 512 + rp * 8) = u0;        // hi=0 half
    *(u32x4*)(astage + kc * 512 + 256 + rp * 8) = u1;  // hi=1 half
  }
  __syncthreads();

  const int lo = hi * 256 + il * 8;
  bf16x8 af[8];
  #pragma unroll
  for (int ks = 0; ks < 8; ++ks)
    af[ks] = *(const bf16x8*)(astage + ks * 512 + lo);

  const uint16_t* WB = WTf + (size_t)(by * 16 + w * 4) * 4096;
  f32x16 acc0 = {}, acc1 = {}, acc2 = {}, acc3 = {};
  #pragma unroll
  for (int ks = 0; ks < 8; ++ks) {
    bf16x8 b0 = *(const bf16x8*)(WB + 0 * 4096 + ks * 512 + lo);
    bf16x8 b1 = *(const bf16x8*)(WB + 1 * 4096 + ks * 512 + lo);
    bf16x8 b2 = *(const bf16x8*)(WB + 2 * 4096 + ks * 512 + lo);
    bf16x8 b3 = *(const bf16x8*)(WB + 3 * 4096 + ks * 512 + lo);
    acc0 = __builtin_amdgcn_mfma_f32_32x32x16_bf16(af[ks], b0, acc0, 0, 0, 0);
    acc1 = __builtin_amdgcn_mfma_f32_32x32x16_bf16(af[ks], b1, acc1, 0, 0, 0);
    acc2 = __builtin_amdgcn_mfma_f32_32x32x16_bf16(af[ks], b2, acc2, 0, 0, 0);
    acc3 = __builtin_amdgcn_mfma_f32_32x32x16_bf16(af[ks], b3, acc3, 0, 0, 0);
  }

  // ---- stage into LDS in destination layout (local col lc) ----
  #pragma unroll
  for (int nt = 0; nt < 4; ++nt) {
    const f32x16 acc = (nt == 0) ? acc0 : (nt == 1) ? acc1 : (nt == 2) ? acc2 : acc3;
    const int lc = w * 128 + nt * 32 + il;
    const float bval = bias[by * 512 + lc];
    int cm;
    if (!vlayout) {
      const int c = (lc >> 3) & 1;
      cm = (c * 256 + (lc >> 4) * 8 + (lc & 7)) ^ (c << 4);
    } else {
      cm = ((lc >> 7) & 3) * 128 + (lc & 15) * 8 + ((lc >> 4) & 7);
    }
    #pragma unroll
    for (int r = 0; r < 16; r += 2) {
      const int rr0 = crow4(r, hi);              // r even: rr1 = rr0+1
      const uint32_t pk = cvt_pk_bf16((acc[r] + bval) * cs, (acc[r + 1] + bval) * cs);
      tile[rr0 * 512 + cm] = (uint16_t)pk;
      tile[(rr0 + 1) * 512 + cm] = (uint16_t)(pk >> 16);
    }
  }
  __syncthreads();

  // ---- coalesced store: 2048 16B-units, 8 per thread ----
  #pragma unroll
  for (int kk2 = 0; kk2 < 8; ++kk2) {
    const int u = t + kk2 * 256;
    const int rr = u >> 6, qq = u & 63;
    int toff;
    size_t gaddr;
    const size_t n = rowbase + rr;
    if (!vlayout) {
      toff = (qq * 8) ^ ((qq >> 5) << 4);   // undo stage swizzle
      gaddr = n * 2048 + (size_t)(qq >> 5) * 1024 + (size_t)by * 256 + (qq & 31) * 8;
    } else {
      toff = qq * 8;
      gaddr = n * 2048 + (size_t)by * 512 + (size_t)(qq >> 4) * 128 + (qq & 15) * 8;
    }
    u32x4 val = *(const u32x4*)(tile + rr * 512 + toff);
    *(u32x4*)(dst + gaddr) = val;
  }
}

// ---------------- Kernel 2: per-token attention ----------------
// 4 tokens/block (grid 2048), 4 waves/block. Per token: wave w owns j-strip
// [32w,32w+32): S^T strip = k3 · q3^T (4 MFMA), softmax over i (DPP + swizzle),
// pack P into B-operand frags (lane-local cvt_pk) -> LDS exchange, barrier,
// wave w then owns i-tile w: O^T = V · P (8 MFMA over all j), direct out3
// store from accumulator. Next-token af/bq prefetched under softmax.
// Exchange layout (dword units): [strip w'][mi][sh][hi_r][il][p] =
//   w'*2048 + mi*512 + sh*256 + hi_r*128 + il*4 + p.
// Writer lane (il,hi_src), tile mi, pk_t (pairs d[2t],d[2t+1]) goes to
//   sh = t>>2, hi_r = (t>>1)&1, p = (t&1) + 2*hi_src  (verified element-wise).
__global__ __launch_bounds__(256) void attn_kernel(
    const uint16_t* q3, const uint16_t* __restrict__ k3,
    const uint16_t* __restrict__ v3, uint16_t* out3) {
  __shared__ uint32_t xch[8192];   // 32 KB
  const int w = threadIdx.x >> 6;
  const int l = threadIdx.x & 63;
  const int il = l & 31, hi = l >> 5;
  const size_t n0 = (size_t)blockIdx.x * 4;
  const uint16_t* qb = q3 + n0 * 2048;
  const uint16_t* kb = k3 + n0 * 2048;
  const uint16_t* vb = v3 + n0 * 2048;
  uint16_t* ob = out3 + n0 * 2048;

  const int aoff = hi * 1024 + (w * 32 + il) * 8;   // k3 A-frag
  const int boff = hi * 1024 + il * 8;              // q3 B-frag (+ mi*256)
  uint32_t* xw = xch + (w * 2048 + il * 4 + hi * 2);        // writer base
  const uint32_t* xr = xch + (w * 512 + hi * 128 + il * 4); // reader base

  bf16x8 af  = *(const bf16x8*)(kb + aoff);
  bf16x8 bq0 = *(const bf16x8*)(qb + boff + 0);
  bf16x8 bq1 = *(const bf16x8*)(qb + boff + 256);
  bf16x8 bq2 = *(const bf16x8*)(qb + boff + 512);
  bf16x8 bq3 = *(const bf16x8*)(qb + boff + 768);

  #pragma unroll 1
  for (int tt = 0; tt < 4; ++tt) {
    // ---- S^T strip: d[mi] = k_strip · q_tile(mi) ----
    f32x16 d0 = {}, d1 = {}, d2 = {}, d3 = {};
    d0 = __builtin_amdgcn_mfma_f32_32x32x16_bf16(af, bq0, d0, 0, 0, 0);
    d1 = __builtin_amdgcn_mfma_f32_32x32x16_bf16(af, bq1, d1, 0, 0, 0);
    d2 = __builtin_amdgcn_mfma_f32_32x32x16_bf16(af, bq2, d2, 0, 0, 0);
    d3 = __builtin_amdgcn_mfma_f32_32x32x16_bf16(af, bq3, d3, 0, 0, 0);
    // ---- prefetch next token's af/bq (clamped; last iter redundant) ----
    const int tn = (tt < 3) ? tt + 1 : 3;
    bf16x8 afn = *(const bf16x8*)(kb + tn * 2048 + aoff);
    bf16x8 bn0 = *(const bf16x8*)(qb + tn * 2048 + boff + 0);
    bf16x8 bn1 = *(const bf16x8*)(qb + tn * 2048 + boff + 256);
    bf16x8 bn2 = *(const bf16x8*)(qb + tn * 2048 + boff + 512);
    bf16x8 bn3 = *(const bf16x8*)(qb + tn * 2048 + boff + 768);
    // ---- softmax over i (row j = 32w + crow4(r,hi)); scale folded in q3 ----
    #pragma unroll
    for (int r = 0; r < 16; ++r) {
      float e0 = v_exp(d0[r]), e1 = v_exp(d1[r]);
      float e2 = v_exp(d2[r]), e3 = v_exp(d3[r]);
      float s = (e0 + e1) + (e2 + e3);
      s = dpp_add<0xB1>(s);    // quad_perm xor1
      s = dpp_add<0x4E>(s);    // quad_perm xor2
      s = dpp_add<0x124>(s);   // row_ror:4
      s = dpp_add<0x128>(s);   // row_ror:8  -> 16-lane row sum
      s += __builtin_bit_cast(float,
             __builtin_amdgcn_ds_swizzle(__builtin_bit_cast(int, s), 0x401F));
      const float rs = __builtin_amdgcn_rcpf(s);
      d0[r] = e0 * rs; d1[r] = e1 * rs; d2[r] = e2 * rs; d3[r] = e3 * rs;
    }
    // ---- pack P -> B-frag dword pairs, write to LDS (all u32-typed) ----
    #define PACK_WRITE(dm, mi_) do {                                           \
      u32x2 q01 = { cvt_pk_bf16(dm[0],  dm[1]),  cvt_pk_bf16(dm[2],  dm[3])  };\
      u32x2 q23 = { cvt_pk_bf16(dm[4],  dm[5]),  cvt_pk_bf16(dm[6],  dm[7])  };\
      u32x2 q45 = { cvt_pk_bf16(dm[8],  dm[9]),  cvt_pk_bf16(dm[10], dm[11]) };\
      u32x2 q67 = { cvt_pk_bf16(dm[12], dm[13]), cvt_pk_bf16(dm[14], dm[15]) };\
      uint32_t* wp_ = xw + (mi_) * 512;                                        \
      *(u32x2*)(wp_ + 0)   = q01;                                              \
      *(u32x2*)(wp_ + 128) = q23;                                              \
      *(u32x2*)(wp_ + 256) = q45;                                              \
      *(u32x2*)(wp_ + 384) = q67;                                              \
    } while (0)
    PACK_WRITE(d0, 0); PACK_WRITE(d1, 1); PACK_WRITE(d2, 2); PACK_WRITE(d3, 3);
    #undef PACK_WRITE
    // ---- V A-frags: lane (il,hi) holds V[j=16ks+8hi+c][h=il&15] ----
    const uint16_t* vt = vb + tt * 2048 + (il & 15) * 8;
    bf16x8 vf0 = *(const bf16x8*)(vt + (0 + hi) * 128);
    bf16x8 vf1 = *(const bf16x8*)(vt + (2 + hi) * 128);
    bf16x8 vf2 = *(const bf16x8*)(vt + (4 + hi) * 128);
    bf16x8 vf3 = *(const bf16x8*)(vt + (6 + hi) * 128);
    bf16x8 vf4 = *(const bf16x8*)(vt + (8 + hi) * 128);
    bf16x8 vf5 = *(const bf16x8*)(vt + (10 + hi) * 128);
    bf16x8 vf6 = *(const bf16x8*)(vt + (12 + hi) * 128);
    bf16x8 vf7 = *(const bf16x8*)(vt + (14 + hi) * 128);
    __syncthreads();
    // ---- O^T = V · P : 8 MFMAs (strip ks>>1, half ks&1) ----
    f32x16 ot = {};
    u32x4 pf;
    pf = *(const u32x4*)(xr + 0 * 2048 + 0 * 256);
    ot = __builtin_amdgcn_mfma_f32_32x32x16_bf16(vf0, __builtin_bit_cast(bf16x8, pf), ot, 0, 0, 0);
    pf = *(const u32x4*)(xr + 0 * 2048 + 1 * 256);
    ot = __builtin_amdgcn_mfma_f32_32x32x16_bf16(vf1, __builtin_bit_cast(bf16x8, pf), ot, 0, 0, 0);
    pf = *(const u32x4*)(xr + 1 * 2048 + 0 * 256);
    ot = __builtin_amdgcn_mfma_f32_32x32x16_bf16(vf2, __builtin_bit_cast(bf16x8, pf), ot, 0, 0, 0);
    pf = *(const u32x4*)(xr + 1 * 2048 + 1 * 256);
    ot = __builtin_amdgcn_mfma_f32_32x32x16_bf16(vf3, __builtin_bit_cast(bf16x8, pf), ot, 0, 0, 0);
    pf = *(const u32x4*)(xr + 2 * 2048 + 0 * 256);
    ot = __builtin_amdgcn_mfma_f32_32x32x16_bf16(vf4, __builtin_bit_cast(bf16x8, pf), ot, 0, 0, 0);
    pf = *(const u32x4*)(xr + 2 * 2048 + 1 * 256);
    ot = __builtin_amdgcn_mfma_f32_32x32x16_bf16(vf5, __builtin_bit_cast(bf16x8, pf), ot, 0, 0, 0);
    pf = *(const u32x4*)(xr + 3 * 2048 + 0 * 256);
    ot = __builtin_amdgcn_mfma_f32_32x32x16_bf16(vf6, __builtin_bit_cast(bf16x8, pf), ot, 0, 0, 0);
    pf = *(const u32x4*)(xr + 3 * 2048 + 1 * 256);
    ot = __builtin_amdgcn_mfma_f32_32x32x16_bf16(vf7, __builtin_bit_cast(bf16x8, pf), ot, 0, 0, 0);
    // ---- store: lane holds col i = 32w+il, rows h = crow4(r,hi) (r 0..7) ----
    uint16_t* op = ob + tt * 2048 + (size_t)(w * 32 + il) * 16;
    *(uint32_t*)(op + 4 * hi + 0)  = cvt_pk_bf16(ot[0], ot[1]);   // h = 4hi, 4hi+1
    *(uint32_t*)(op + 4 * hi + 2)  = cvt_pk_bf16(ot[2], ot[3]);   // h = 4hi+2,3
    *(uint32_t*)(op + 4 * hi + 8)  = cvt_pk_bf16(ot[4], ot[5]);   // h = 8+4hi,+1
    *(uint32_t*)(op + 4 * hi + 10) = cvt_pk_bf16(ot[6], ot[7]);   // h = 8+4hi+2,3
    __syncthreads();   // protect LDS reuse next token
    af = afn; bq0 = bn0; bq1 = bn1; bq2 = bn2; bq3 = bn3;
  }
}

// ---------------- Kernel 3: output projection ----------------
// out = out3[8192x2048](bf16) @ Wo + bo, f32 out. K-split 2 per block.
__global__ __launch_bounds__(512) void outproj_kernel(
    const uint16_t* __restrict__ out3, const uint16_t* __restrict__ WoT,
    const float* __restrict__ bo, float* __restrict__ out) {
  __shared__ float part[4][32][32];
  const int w = threadIdx.x >> 6;
  const int l = threadIdx.x & 63;
  const int il = l & 31, hi = l >> 5;
  const int nt = w >> 1, ksv = w & 1;
  const int rowbase = blockIdx.x * 32;
  f32x16 acc = {};
  #pragma unroll 4
  for (int kb = 0; kb < 64; ++kb) {
    const int kk = ksv * 1024 + kb * 16 + hi * 8;
    bf16x8 afr = *(const bf16x8*)(out3 + (size_t)(rowbase + il) * DH + kk);
    bf16x8 bfr = *(const bf16x8*)(WoT + (size_t)(nt * 32 + il) * DH + kk);
    acc = __builtin_amdgcn_mfma_f32_32x32x16_bf16(afr, bfr, acc, 0, 0, 0);
  }
  if (ksv == 1) {
    #pragma unroll
    for (int r = 0; r < 16; ++r) part[nt][crow4(r, hi)][il] = acc[r];
  }
  __syncthreads();
  if (ksv == 0) {
    const int col = nt * 32 + il;
    const float bval = bo[col];
    #pragma unroll
    for (int r = 0; r < 16; ++r) {
      const int rr = crow4(r, hi);
      out[(size_t)(rowbase + rr) * DDIM + col] = acc[r] + part[nt][rr][il] + bval;
    }
  }
}

extern "C" void kernel_launch(void* const* d_in, const int* in_sizes, int n_in,
                              void* d_out, int out_size, void* d_ws, size_t ws_size,
                              hipStream_t stream) {
  (void)in_sizes; (void)n_in; (void)out_size; (void)ws_size;
  const float* q  = (const float*)d_in[0];
  const float* k  = (const float*)d_in[1];
  const float* v  = (const float*)d_in[2];
  const float* Wq = (const float*)d_in[3];
  const float* bq = (const float*)d_in[4];
  const float* Wk = (const float*)d_in[5];
  const float* bk = (const float*)d_in[6];
  const float* Wv = (const float*)d_in[7];
  const float* bv = (const float*)d_in[8];
  const float* Wo = (const float*)d_in[9];
  const float* bo = (const float*)d_in[10];
  float* out = (float*)d_out;

  char* ws = (char*)d_ws;
  const size_t MB = 1024ull * 1024ull;
  uint16_t* q3  = (uint16_t*)(ws);             // 32MB; becomes out3
  uint16_t* k3  = (uint16_t*)(ws + 32 * MB);
  uint16_t* v3  = (uint16_t*)(ws + 64 * MB);
  uint16_t* WqT = (uint16_t*)(ws + 96 * MB);   // 512KB each
  uint16_t* WkT = WqT + (size_t)DH * 128;
  uint16_t* WvT = WkT + (size_t)DH * 128;
  uint16_t* WoT = WvT + (size_t)DH * 128;

  prep_weights<<<dim3(8, 4), 256, 0, stream>>>(Wq, Wk, Wv, Wo, WqT, WkT, WvT, WoT);
  proj_kernel<<<dim3(256, 4, 3), 256, 0, stream>>>(q, k, v, WqT, WkT, WvT,
                                                   bq, bk, bv, q3, k3, v3);
  attn_kernel<<<dim3(2048), 256, 0, stream>>>(q3, k3, v3, q3);
  outproj_kernel<<<dim3(256), 512, 0, stream>>>(q3, WoT, bo, out);
}

// Round 8
// 118.801 us; speedup vs baseline: 1.1985x; 1.0199x over previous
//
#include <hip/hip_runtime.h>
#include <hip/hip_bf16.h>
#include <stdint.h>

// Problem: N=8192 tokens, D=128, HEADS=16, dh=2048.
// Pipeline: prep weights (fragment-major WT) -> q3/k3/v3 projections
//           (q3 pre-scaled by log2(e)/sqrt(D)) -> per-token attention
//           (strip softmax + P-fragment LDS exchange + O^T=V*P) -> outproj.
//
// ws layout (~98 MB):
//   [0,32M)   q3  bf16 [n]{(h>>3)*1024 + i*8 + (h&7)}  (scaled by CEXP)
//             -- later overwritten by out3 [n][f]
//   [32,64M)  k3  bf16 same layout (unscaled)
//   [64,96M)  v3  bf16 [n]{(j>>3)*128 + h*8 + (j&7)}   (fragment units for PV)
//   [96M..)   WTq/WTk/WTv bf16 frag-major [g(64)][ks(8)][hi(2)][il(32)][8],
//             WoT bf16 [128 col][2048 k]

#define NTOK 8192
#define DDIM 128
#define DH   2048

typedef float    f32x16 __attribute__((ext_vector_type(16)));
typedef float    f32x4  __attribute__((ext_vector_type(4)));
typedef __bf16   bf16x8 __attribute__((ext_vector_type(8)));
typedef uint32_t u32x4  __attribute__((ext_vector_type(4)));
typedef uint32_t u32x2  __attribute__((ext_vector_type(2)));

static __device__ __forceinline__ uint32_t cvt_pk_bf16(float lo, float hi) {
  uint32_t r;
  asm("v_cvt_pk_bf16_f32 %0, %1, %2" : "=v"(r) : "v"(lo), "v"(hi));
  return r;
}
static __device__ __forceinline__ float v_exp(float x) {
  float r;
  asm("v_exp_f32 %0, %1" : "=v"(r) : "v"(x));
  return r;
}
// C/D row mapping for mfma_f32_32x32x16: row = (r&3) + 8*(r>>2) + 4*hi, col = lane&31
static __device__ __forceinline__ int crow4(int r, int hi) {
  return (r & 3) + 8 * (r >> 2) + 4 * hi;
}
// Fusable DPP add step: s + dpp(s). GCNDPPCombine folds mov_dpp+add -> v_add_f32_dpp.
template <int CTRL>
static __device__ __forceinline__ float dpp_add(float s) {
  int t = __builtin_amdgcn_update_dpp(0, __builtin_bit_cast(int, s), CTRL, 0xf, 0xf, true);
  return s + __builtin_bit_cast(float, t);
}

// ---------------- Kernel 0: weight prep ----------------
// Wq/Wk/Wv f32 [128][2048] -> WT bf16 frag-major: [g=col>>5][ks][hi][il=col&31][8]
// Wo f32 [2048][128] -> WoT bf16 [128 col][2048 k]
__global__ __launch_bounds__(256) void prep_weights(
    const float* __restrict__ Wq, const float* __restrict__ Wk,
    const float* __restrict__ Wv, const float* __restrict__ Wo,
    uint16_t* __restrict__ WqT, uint16_t* __restrict__ WkT,
    uint16_t* __restrict__ WvT, uint16_t* __restrict__ WoT) {
  const int t = threadIdx.x, bx = blockIdx.x, z = blockIdx.y;
  if (z < 3) {
    const float* W = (z == 0) ? Wq : (z == 1) ? Wk : Wv;
    uint16_t* WT = (z == 0) ? WqT : (z == 1) ? WkT : WvT;
    const int col = bx * 256 + t;
    const int g = col >> 5, il = col & 31;
    for (int kc = 0; kc < 16; ++kc) {   // kc = k>>3 : ks = kc>>1, hi = kc&1
      u32x4 wv;
      #pragma unroll
      for (int p = 0; p < 4; ++p) {
        float f0 = W[(size_t)(kc * 8 + 2 * p) * DH + col];
        float f1 = W[(size_t)(kc * 8 + 2 * p + 1) * DH + col];
        wv[p] = cvt_pk_bf16(f0, f1);
      }
      *(u32x4*)(WT + (size_t)g * 4096 + (kc >> 1) * 512 + (kc & 1) * 256 + il * 8) = wv;
    }
  } else {
    const int col = t & 127, ksub = t >> 7;
    const int kbase = bx * 256 + ksub * 128;
    for (int kc = 0; kc < 16; ++kc) {
      const int k0 = kbase + kc * 8;
      u32x4 wv;
      #pragma unroll
      for (int p = 0; p < 4; ++p) {
        float f0 = Wo[(size_t)(k0 + 2 * p) * DDIM + col];
        float f1 = Wo[(size_t)(k0 + 2 * p + 1) * DDIM + col];
        wv[p] = cvt_pk_bf16(f0, f1);
      }
      *(u32x4*)(WoT + (size_t)col * DH + k0) = wv;
    }
  }
}

// ---------------- Kernel 1: Q/K/V projections ----------------
// C = A[8192x128] @ W[128x2048] + b, bf16 out in attention layouts.
// q3/k3 unit: idx = n*2048 + (h>>3)*1024 + i*8 + (h&7)        (f = i*16+h)
// v3   unit: idx = n*2048 + (j>>3)*128 + h*8 + (j&7)          (f = j*16+h)
// q3 is additionally scaled by CEXP = log2(e)/sqrt(128) (folded softmax scale).
__global__ __launch_bounds__(256, 3) void proj_kernel(
    const float* __restrict__ q, const float* __restrict__ kin,
    const float* __restrict__ v,
    const uint16_t* __restrict__ WqT, const uint16_t* __restrict__ WkT,
    const uint16_t* __restrict__ WvT,
    const float* __restrict__ bq, const float* __restrict__ bk,
    const float* __restrict__ bv,
    uint16_t* __restrict__ q3, uint16_t* __restrict__ k3,
    uint16_t* __restrict__ v3) {
  __shared__ uint16_t astage[4096];    // A tile, frag layout [ks][hi][il][8]
  __shared__ uint16_t tile[32 * 512];  // 32 KB destination-layout staging
  const int z = blockIdx.z;
  const float* A = (z == 0) ? q : (z == 1) ? kin : v;
  const uint16_t* WTf = (z == 0) ? WqT : (z == 1) ? WkT : WvT;
  const float* bias = (z == 0) ? bq : (z == 1) ? bk : bv;
  uint16_t* dst = (z == 0) ? q3 : (z == 1) ? k3 : v3;
  const bool vlayout = (z == 2);
  const float CEXP = 1.4426950408889634f * 0.08838834764831845f;
  const float cs = (z == 0) ? CEXP : 1.0f;

  const int t = threadIdx.x;
  const int w = t >> 6, l = t & 63;
  const int il = l & 31, hi = l >> 5;
  const int T = blockIdx.x, by = blockIdx.y;
  const int rowbase = T * 32;

  // ---- stage A tile (32x128 f32 -> bf16 frag layout), coalesced ----
  {
    const int rp = t >> 3, kc = t & 7;
    const float* ap = A + ((size_t)rowbase + rp) * DDIM + kc * 16;
    float4 f0 = *(const float4*)(ap + 0);
    float4 f1 = *(const float4*)(ap + 4);
    float4 f2 = *(const float4*)(ap + 8);
    float4 f3 = *(const float4*)(ap + 12);
    u32x4 u0 = { cvt_pk_bf16(f0.x, f0.y), cvt_pk_bf16(f0.z, f0.w),
                 cvt_pk_bf16(f1.x, f1.y), cvt_pk_bf16(f1.z, f1.w) };
    u32x4 u1 = { cvt_pk_bf16(f2.x, f2.y), cvt_pk_bf16(f2.z, f2.w),
                 cvt_pk_bf16(f3.x, f3.y), cvt_pk_bf16(f3.z, f3.w) };
    *(u32x4*)(astage + kc * 512 + rp * 8) = u0;        // hi=0 half
    *(u32x4*)(astage + kc * 512 + 256 + rp * 8) = u1;  // hi=1 half
  }
  __syncthreads();

  const int lo = hi * 256 + il * 8;
  bf16x8 af[8];
  #pragma unroll
  for (int ks = 0; ks < 8; ++ks)
    af[ks] = *(const bf16x8*)(astage + ks * 512 + lo);

  const uint16_t* WB = WTf + (size_t)(by * 16 + w * 4) * 4096;
  f32x16 acc0 = {}, acc1 = {}, acc2 = {}, acc3 = {};
  #pragma unroll
  for (int ks = 0; ks < 8; ++ks) {
    bf16x8 b0 = *(const bf16x8*)(WB + 0 * 4096 + ks * 512 + lo);
    bf16x8 b1 = *(const bf16x8*)(WB + 1 * 4096 + ks * 512 + lo);
    bf16x8 b2 = *(const bf16x8*)(WB + 2 * 4096 + ks * 512 + lo);
    bf16x8 b3 = *(const bf16x8*)(WB + 3 * 4096 + ks * 512 + lo);
    acc0 = __builtin_amdgcn_mfma_f32_32x32x16_bf16(af[ks], b0, acc0, 0, 0, 0);
    acc1 = __builtin_amdgcn_mfma_f32_32x32x16_bf16(af[ks], b1, acc1, 0, 0, 0);
    acc2 = __builtin_amdgcn_mfma_f32_32x32x16_bf16(af[ks], b2, acc2, 0, 0, 0);
    acc3 = __builtin_amdgcn_mfma_f32_32x32x16_bf16(af[ks], b3, acc3, 0, 0, 0);
  }

  // ---- stage into LDS in destination layout (local col lc) ----
  #pragma unroll
  for (int nt = 0; nt < 4; ++nt) {
    const f32x16 acc = (nt == 0) ? acc0 : (nt == 1) ? acc1 : (nt == 2) ? acc2 : acc3;
    const int lc = w * 128 + nt * 32 + il;
    const float bval = bias[by * 512 + lc];
    int cm;
    if (!vlayout) {
      const int c = (lc >> 3) & 1;
      cm = (c * 256 + (lc >> 4) * 8 + (lc & 7)) ^ (c << 4);
    } else {
      cm = ((lc >> 7) & 3) * 128 + (lc & 15) * 8 + ((lc >> 4) & 7);
    }
    #pragma unroll
    for (int r = 0; r < 16; r += 2) {
      const int rr0 = crow4(r, hi);              // r even: rr1 = rr0+1
      const uint32_t pk = cvt_pk_bf16((acc[r] + bval) * cs, (acc[r + 1] + bval) * cs);
      tile[rr0 * 512 + cm] = (uint16_t)pk;
      tile[(rr0 + 1) * 512 + cm] = (uint16_t)(pk >> 16);
    }
  }
  __syncthreads();

  // ---- coalesced store: 2048 16B-units, 8 per thread ----
  #pragma unroll
  for (int kk2 = 0; kk2 < 8; ++kk2) {
    const int u = t + kk2 * 256;
    const int rr = u >> 6, qq = u & 63;
    int toff;
    size_t gaddr;
    const size_t n = rowbase + rr;
    if (!vlayout) {
      toff = (qq * 8) ^ ((qq >> 5) << 4);   // undo stage swizzle
      gaddr = n * 2048 + (size_t)(qq >> 5) * 1024 + (size_t)by * 256 + (qq & 31) * 8;
    } else {
      toff = qq * 8;
      gaddr = n * 2048 + (size_t)by * 512 + (size_t)(qq >> 4) * 128 + (qq & 15) * 8;
    }
    u32x4 val = *(const u32x4*)(tile + rr * 512 + toff);
    *(u32x4*)(dst + gaddr) = val;
  }
}

// ---------------- Kernel 2: per-token attention ----------------
// 8 tokens/block (grid 1024), 4 waves/block. Per token: wave w owns j-strip
// [32w,32w+32): S^T strip = k3 · q3^T (4 MFMA), softmax over i (DPP + swizzle),
// pack P into B-operand frags (lane-local cvt_pk) -> LDS exchange, barrier,
// wave w then owns i-tile w: O^T = V · P (8 MFMA over all j), direct out3
// store from accumulator. vf loads hoisted to the top of the iteration
// (latency covered by QK+softmax+pack; __syncthreads fences them from
// sinking); next-token af/bq prefetched under softmax.
// Exchange layout (dword units): [strip w'][mi][sh][hi_r][il][p] =
//   w'*2048 + mi*512 + sh*256 + hi_r*128 + il*4 + p.
// Writer lane (il,hi_src), tile mi, pk_t (pairs d[2t],d[2t+1]) goes to
//   sh = t>>2, hi_r = (t>>1)&1, p = (t&1) + 2*hi_src  (verified element-wise).
__global__ __launch_bounds__(256) void attn_kernel(
    const uint16_t* q3, const uint16_t* __restrict__ k3,
    const uint16_t* __restrict__ v3, uint16_t* out3) {
  __shared__ uint32_t xch[8192];   // 32 KB
  const int w = threadIdx.x >> 6;
  const int l = threadIdx.x & 63;
  const int il = l & 31, hi = l >> 5;
  const size_t n0 = (size_t)blockIdx.x * 8;
  const uint16_t* qb = q3 + n0 * 2048;
  const uint16_t* kb = k3 + n0 * 2048;
  const uint16_t* vb = v3 + n0 * 2048;
  uint16_t* ob = out3 + n0 * 2048;

  const int aoff = hi * 1024 + (w * 32 + il) * 8;   // k3 A-frag
  const int boff = hi * 1024 + il * 8;              // q3 B-frag (+ mi*256)
  uint32_t* xw = xch + (w * 2048 + il * 4 + hi * 2);        // writer base
  const uint32_t* xr = xch + (w * 512 + hi * 128 + il * 4); // reader base

  bf16x8 af  = *(const bf16x8*)(kb + aoff);
  bf16x8 bq0 = *(const bf16x8*)(qb + boff + 0);
  bf16x8 bq1 = *(const bf16x8*)(qb + boff + 256);
  bf16x8 bq2 = *(const bf16x8*)(qb + boff + 512);
  bf16x8 bq3 = *(const bf16x8*)(qb + boff + 768);

  #pragma unroll 1
  for (int tt = 0; tt < 8; ++tt) {
    // ---- V A-frags issued FIRST: latency covered by QK+softmax+pack ----
    const uint16_t* vt = vb + tt * 2048 + (il & 15) * 8;
    bf16x8 vf0 = *(const bf16x8*)(vt + (0 + hi) * 128);
    bf16x8 vf1 = *(const bf16x8*)(vt + (2 + hi) * 128);
    bf16x8 vf2 = *(const bf16x8*)(vt + (4 + hi) * 128);
    bf16x8 vf3 = *(const bf16x8*)(vt + (6 + hi) * 128);
    bf16x8 vf4 = *(const bf16x8*)(vt + (8 + hi) * 128);
    bf16x8 vf5 = *(const bf16x8*)(vt + (10 + hi) * 128);
    bf16x8 vf6 = *(const bf16x8*)(vt + (12 + hi) * 128);
    bf16x8 vf7 = *(const bf16x8*)(vt + (14 + hi) * 128);
    // ---- S^T strip: d[mi] = k_strip · q_tile(mi) ----
    f32x16 d0 = {}, d1 = {}, d2 = {}, d3 = {};
    d0 = __builtin_amdgcn_mfma_f32_32x32x16_bf16(af, bq0, d0, 0, 0, 0);
    d1 = __builtin_amdgcn_mfma_f32_32x32x16_bf16(af, bq1, d1, 0, 0, 0);
    d2 = __builtin_amdgcn_mfma_f32_32x32x16_bf16(af, bq2, d2, 0, 0, 0);
    d3 = __builtin_amdgcn_mfma_f32_32x32x16_bf16(af, bq3, d3, 0, 0, 0);
    // ---- prefetch next token's af/bq (clamped; last iter redundant) ----
    const int tn = (tt < 7) ? tt + 1 : 7;
    bf16x8 afn = *(const bf16x8*)(kb + tn * 2048 + aoff);
    bf16x8 bn0 = *(const bf16x8*)(qb + tn * 2048 + boff + 0);
    bf16x8 bn1 = *(const bf16x8*)(qb + tn * 2048 + boff + 256);
    bf16x8 bn2 = *(const bf16x8*)(qb + tn * 2048 + boff + 512);
    bf16x8 bn3 = *(const bf16x8*)(qb + tn * 2048 + boff + 768);
    // ---- softmax over i (row j = 32w + crow4(r,hi)); scale folded in q3 ----
    #pragma unroll
    for (int r = 0; r < 16; ++r) {
      float e0 = v_exp(d0[r]), e1 = v_exp(d1[r]);
      float e2 = v_exp(d2[r]), e3 = v_exp(d3[r]);
      float s = (e0 + e1) + (e2 + e3);
      s = dpp_add<0xB1>(s);    // quad_perm xor1
      s = dpp_add<0x4E>(s);    // quad_perm xor2
      s = dpp_add<0x124>(s);   // row_ror:4
      s = dpp_add<0x128>(s);   // row_ror:8  -> 16-lane row sum
      s += __builtin_bit_cast(float,
             __builtin_amdgcn_ds_swizzle(__builtin_bit_cast(int, s), 0x401F));
      const float rs = __builtin_amdgcn_rcpf(s);
      d0[r] = e0 * rs; d1[r] = e1 * rs; d2[r] = e2 * rs; d3[r] = e3 * rs;
    }
    // ---- pack P -> B-frag dword pairs, write to LDS (all u32-typed) ----
    #define PACK_WRITE(dm, mi_) do {                                           \
      u32x2 q01 = { cvt_pk_bf16(dm[0],  dm[1]),  cvt_pk_bf16(dm[2],  dm[3])  };\
      u32x2 q23 = { cvt_pk_bf16(dm[4],  dm[5]),  cvt_pk_bf16(dm[6],  dm[7])  };\
      u32x2 q45 = { cvt_pk_bf16(dm[8],  dm[9]),  cvt_pk_bf16(dm[10], dm[11]) };\
      u32x2 q67 = { cvt_pk_bf16(dm[12], dm[13]), cvt_pk_bf16(dm[14], dm[15]) };\
      uint32_t* wp_ = xw + (mi_) * 512;                                        \
      *(u32x2*)(wp_ + 0)   = q01;                                              \
      *(u32x2*)(wp_ + 128) = q23;                                              \
      *(u32x2*)(wp_ + 256) = q45;                                              \
      *(u32x2*)(wp_ + 384) = q67;                                              \
    } while (0)
    PACK_WRITE(d0, 0); PACK_WRITE(d1, 1); PACK_WRITE(d2, 2); PACK_WRITE(d3, 3);
    #undef PACK_WRITE
    __syncthreads();
    // ---- O^T = V · P : 8 MFMAs (strip ks>>1, half ks&1) ----
    f32x16 ot = {};
    u32x4 pf;
    pf = *(const u32x4*)(xr + 0 * 2048 + 0 * 256);
    ot = __builtin_amdgcn_mfma_f32_32x32x16_bf16(vf0, __builtin_bit_cast(bf16x8, pf), ot, 0, 0, 0);
    pf = *(const u32x4*)(xr + 0 * 2048 + 1 * 256);
    ot = __builtin_amdgcn_mfma_f32_32x32x16_bf16(vf1, __builtin_bit_cast(bf16x8, pf), ot, 0, 0, 0);
    pf = *(const u32x4*)(xr + 1 * 2048 + 0 * 256);
    ot = __builtin_amdgcn_mfma_f32_32x32x16_bf16(vf2, __builtin_bit_cast(bf16x8, pf), ot, 0, 0, 0);
    pf = *(const u32x4*)(xr + 1 * 2048 + 1 * 256);
    ot = __builtin_amdgcn_mfma_f32_32x32x16_bf16(vf3, __builtin_bit_cast(bf16x8, pf), ot, 0, 0, 0);
    pf = *(const u32x4*)(xr + 2 * 2048 + 0 * 256);
    ot = __builtin_amdgcn_mfma_f32_32x32x16_bf16(vf4, __builtin_bit_cast(bf16x8, pf), ot, 0, 0, 0);
    pf = *(const u32x4*)(xr + 2 * 2048 + 1 * 256);
    ot = __builtin_amdgcn_mfma_f32_32x32x16_bf16(vf5, __builtin_bit_cast(bf16x8, pf), ot, 0, 0, 0);
    pf = *(const u32x4*)(xr + 3 * 2048 + 0 * 256);
    ot = __builtin_amdgcn_mfma_f32_32x32x16_bf16(vf6, __builtin_bit_cast(bf16x8, pf), ot, 0, 0, 0);
    pf = *(const u32x4*)(xr + 3 * 2048 + 1 * 256);
    ot = __builtin_amdgcn_mfma_f32_32x32x16_bf16(vf7, __builtin_bit_cast(bf16x8, pf), ot, 0, 0, 0);
    // ---- store: lane holds col i = 32w+il, rows h = crow4(r,hi) (r 0..7) ----
    uint16_t* op = ob + tt * 2048 + (size_t)(w * 32 + il) * 16;
    *(uint32_t*)(op + 4 * hi + 0)  = cvt_pk_bf16(ot[0], ot[1]);   // h = 4hi, 4hi+1
    *(uint32_t*)(op + 4 * hi + 2)  = cvt_pk_bf16(ot[2], ot[3]);   // h = 4hi+2,3
    *(uint32_t*)(op + 4 * hi + 8)  = cvt_pk_bf16(ot[4], ot[5]);   // h = 8+4hi,+1
    *(uint32_t*)(op + 4 * hi + 10) = cvt_pk_bf16(ot[6], ot[7]);   // h = 8+4hi+2,3
    __syncthreads();   // protect LDS reuse next token
    af = afn; bq0 = bn0; bq1 = bn1; bq2 = bn2; bq3 = bn3;
  }
}

// ---------------- Kernel 3: output projection ----------------
// out = out3[8192x2048](bf16) @ Wo + bo, f32 out. K-split 2 per block.
__global__ __launch_bounds__(512) void outproj_kernel(
    const uint16_t* __restrict__ out3, const uint16_t* __restrict__ WoT,
    const float* __restrict__ bo, float* __restrict__ out) {
  __shared__ float part[4][32][32];
  const int w = threadIdx.x >> 6;
  const int l = threadIdx.x & 63;
  const int il = l & 31, hi = l >> 5;
  const int nt = w >> 1, ksv = w & 1;
  const int rowbase = blockIdx.x * 32;
  f32x16 acc = {};
  #pragma unroll 4
  for (int kb = 0; kb < 64; ++kb) {
    const int kk = ksv * 1024 + kb * 16 + hi * 8;
    bf16x8 afr = *(const bf16x8*)(out3 + (size_t)(rowbase + il) * DH + kk);
    bf16x8 bfr = *(const bf16x8*)(WoT + (size_t)(nt * 32 + il) * DH + kk);
    acc = __builtin_amdgcn_mfma_f32_32x32x16_bf16(afr, bfr, acc, 0, 0, 0);
  }
  if (ksv == 1) {
    #pragma unroll
    for (int r = 0; r < 16; ++r) part[nt][crow4(r, hi)][il] = acc[r];
  }
  __syncthreads();
  if (ksv == 0) {
    const int col = nt * 32 + il;
    const float bval = bo[col];
    #pragma unroll
    for (int r = 0; r < 16; ++r) {
      const int rr = crow4(r, hi);
      out[(size_t)(rowbase + rr) * DDIM + col] = acc[r] + part[nt][rr][il] + bval;
    }
  }
}

extern "C" void kernel_launch(void* const* d_in, const int* in_sizes, int n_in,
                              void* d_out, int out_size, void* d_ws, size_t ws_size,
                              hipStream_t stream) {
  (void)in_sizes; (void)n_in; (void)out_size; (void)ws_size;
  const float* q  = (const float*)d_in[0];
  const float* k  = (const float*)d_in[1];
  const float* v  = (const float*)d_in[2];
  const float* Wq = (const float*)d_in[3];
  const float* bq = (const float*)d_in[4];
  const float* Wk = (const float*)d_in[5];
  const float* bk = (const float*)d_in[6];
  const float* Wv = (const float*)d_in[7];
  const float* bv = (const float*)d_in[8];
  const float* Wo = (const float*)d_in[9];
  const float* bo = (const float*)d_in[10];
  float* out = (float*)d_out;

  char* ws = (char*)d_ws;
  const size_t MB = 1024ull * 1024ull;
  uint16_t* q3  = (uint16_t*)(ws);             // 32MB; becomes out3
  uint16_t* k3  = (uint16_t*)(ws + 32 * MB);
  uint16_t* v3  = (uint16_t*)(ws + 64 * MB);
  uint16_t* WqT = (uint16_t*)(ws + 96 * MB);   // 512KB each
  uint16_t* WkT = WqT + (size_t)DH * 128;
  uint16_t* WvT = WkT + (size_t)DH * 128;
  uint16_t* WoT = WvT + (size_t)DH * 128;

  prep_weights<<<dim3(8, 4), 256, 0, stream>>>(Wq, Wk, Wv, Wo, WqT, WkT, WvT, WoT);
  proj_kernel<<<dim3(256, 4, 3), 256, 0, stream>>>(q, k, v, WqT, WkT, WvT,
                                                   bq, bk, bv, q3, k3, v3);
  attn_kernel<<<dim3(1024), 256, 0, stream>>>(q3, k3, v3, q3);
  outproj_kernel<<<dim3(256), 512, 0, stream>>>(q3, WoT, bo, out);
}

// Round 11
// 112.008 us; speedup vs baseline: 1.2712x; 1.0606x over previous
//
#include <hip/hip_runtime.h>
#include <hip/hip_bf16.h>
#include <stdint.h>

// Problem: N=8192 tokens, D=128, HEADS=16, dh=2048.
// Pipeline: prep weights (fragment-major WT, WoT [col][k]) -> q3/k3/v3
//           projections (q3 pre-scaled by log2(e)/sqrt(D)) -> per-token
//           attention (strip softmax + P-fragment LDS exchange + O^T=V*P)
//           -> outproj (LDS-staged A [FIXED full coverage], WoT B).
//
// ws layout (~98 MB):
//   [0,32M)   q3  bf16 [n]{(h>>3)*1024 + i*8 + (h&7)}  (scaled by CEXP)
//             -- later overwritten by out3 [n][f]
//   [32,64M)  k3  bf16 same layout (unscaled)
//   [64,96M)  v3  bf16 [n]{(j>>3)*128 + h*8 + (j&7)}   (fragment units for PV)
//   [96M..)   WTq/WTk/WTv bf16 frag-major [g(64)][ks(8)][hi(2)][il(32)][8],
//             WoT bf16 [128 col][2048 k]

#define NTOK 8192
#define DDIM 128
#define DH   2048

typedef float    f32x16 __attribute__((ext_vector_type(16)));
typedef float    f32x4  __attribute__((ext_vector_type(4)));
typedef __bf16   bf16x8 __attribute__((ext_vector_type(8)));
typedef uint32_t u32x4  __attribute__((ext_vector_type(4)));
typedef uint32_t u32x2  __attribute__((ext_vector_type(2)));

static __device__ __forceinline__ uint32_t cvt_pk_bf16(float lo, float hi) {
  uint32_t r;
  asm("v_cvt_pk_bf16_f32 %0, %1, %2" : "=v"(r) : "v"(lo), "v"(hi));
  return r;
}
static __device__ __forceinline__ float v_exp(float x) {
  float r;
  asm("v_exp_f32 %0, %1" : "=v"(r) : "v"(x));
  return r;
}
// C/D row mapping for mfma_f32_32x32x16: row = (r&3) + 8*(r>>2) + 4*hi, col = lane&31
static __device__ __forceinline__ int crow4(int r, int hi) {
  return (r & 3) + 8 * (r >> 2) + 4 * hi;
}
// Fusable DPP add step: s + dpp(s). GCNDPPCombine folds mov_dpp+add -> v_add_f32_dpp.
template <int CTRL>
static __device__ __forceinline__ float dpp_add(float s) {
  int t = __builtin_amdgcn_update_dpp(0, __builtin_bit_cast(int, s), CTRL, 0xf, 0xf, true);
  return s + __builtin_bit_cast(float, t);
}

// ---------------- Kernel 0: weight prep ----------------
// Wq/Wk/Wv f32 [128][2048] -> WT bf16 frag-major: [g=col>>5][ks][hi][il=col&31][8]
// Wo f32 [2048][128] -> WoT bf16 [128 col][2048 k]
__global__ __launch_bounds__(256) void prep_weights(
    const float* __restrict__ Wq, const float* __restrict__ Wk,
    const float* __restrict__ Wv, const float* __restrict__ Wo,
    uint16_t* __restrict__ WqT, uint16_t* __restrict__ WkT,
    uint16_t* __restrict__ WvT, uint16_t* __restrict__ WoT) {
  const int t = threadIdx.x, bx = blockIdx.x, z = blockIdx.y;
  if (z < 3) {
    const float* W = (z == 0) ? Wq : (z == 1) ? Wk : Wv;
    uint16_t* WT = (z == 0) ? WqT : (z == 1) ? WkT : WvT;
    const int col = bx * 256 + t;
    const int g = col >> 5, il = col & 31;
    for (int kc = 0; kc < 16; ++kc) {   // kc = k>>3 : ks = kc>>1, hi = kc&1
      u32x4 wv;
      #pragma unroll
      for (int p = 0; p < 4; ++p) {
        float f0 = W[(size_t)(kc * 8 + 2 * p) * DH + col];
        float f1 = W[(size_t)(kc * 8 + 2 * p + 1) * DH + col];
        wv[p] = cvt_pk_bf16(f0, f1);
      }
      *(u32x4*)(WT + (size_t)g * 4096 + (kc >> 1) * 512 + (kc & 1) * 256 + il * 8) = wv;
    }
  } else {
    const int col = t & 127, ksub = t >> 7;
    const int kbase = bx * 256 + ksub * 128;
    for (int kc = 0; kc < 16; ++kc) {
      const int k0 = kbase + kc * 8;
      u32x4 wv;
      #pragma unroll
      for (int p = 0; p < 4; ++p) {
        float f0 = Wo[(size_t)(k0 + 2 * p) * DDIM + col];
        float f1 = Wo[(size_t)(k0 + 2 * p + 1) * DDIM + col];
        wv[p] = cvt_pk_bf16(f0, f1);
      }
      *(u32x4*)(WoT + (size_t)col * DH + k0) = wv;
    }
  }
}

// ---------------- Kernel 1: Q/K/V projections ----------------
// C = A[8192x128] @ W[128x2048] + b, bf16 out in attention layouts.
// q3/k3 unit: idx = n*2048 + (h>>3)*1024 + i*8 + (h&7)        (f = i*16+h)
// v3   unit: idx = n*2048 + (j>>3)*128 + h*8 + (j&7)          (f = j*16+h)
// q3 is additionally scaled by CEXP = log2(e)/sqrt(128) (folded softmax scale).
__global__ __launch_bounds__(256, 3) void proj_kernel(
    const float* __restrict__ q, const float* __restrict__ kin,
    const float* __restrict__ v,
    const uint16_t* __restrict__ WqT, const uint16_t* __restrict__ WkT,
    const uint16_t* __restrict__ WvT,
    const float* __restrict__ bq, const float* __restrict__ bk,
    const float* __restrict__ bv,
    uint16_t* __restrict__ q3, uint16_t* __restrict__ k3,
    uint16_t* __restrict__ v3) {
  __shared__ uint16_t astage[4096];    // A tile, frag layout [ks][hi][il][8]
  __shared__ uint16_t tile[32 * 512];  // 32 KB destination-layout staging
  const int z = blockIdx.z;
  const float* A = (z == 0) ? q : (z == 1) ? kin : v;
  const uint16_t* WTf = (z == 0) ? WqT : (z == 1) ? WkT : WvT;
  const float* bias = (z == 0) ? bq : (z == 1) ? bk : bv;
  uint16_t* dst = (z == 0) ? q3 : (z == 1) ? k3 : v3;
  const bool vlayout = (z == 2);
  const float CEXP = 1.4426950408889634f * 0.08838834764831845f;
  const float cs = (z == 0) ? CEXP : 1.0f;

  const int t = threadIdx.x;
  const int w = t >> 6, l = t & 63;
  const int il = l & 31, hi = l >> 5;
  const int T = blockIdx.x, by = blockIdx.y;
  const int rowbase = T * 32;

  // ---- stage A tile (32x128 f32 -> bf16 frag layout), coalesced ----
  {
    const int rp = t >> 3, kc = t & 7;
    const float* ap = A + ((size_t)rowbase + rp) * DDIM + kc * 16;
    float4 f0 = *(const float4*)(ap + 0);
    float4 f1 = *(const float4*)(ap + 4);
    float4 f2 = *(const float4*)(ap + 8);
    float4 f3 = *(const float4*)(ap + 12);
    u32x4 u0 = { cvt_pk_bf16(f0.x, f0.y), cvt_pk_bf16(f0.z, f0.w),
                 cvt_pk_bf16(f1.x, f1.y), cvt_pk_bf16(f1.z, f1.w) };
    u32x4 u1 = { cvt_pk_bf16(f2.x, f2.y), cvt_pk_bf16(f2.z, f2.w),
                 cvt_pk_bf16(f3.x, f3.y), cvt_pk_bf16(f3.z, f3.w) };
    *(u32x4*)(astage + kc * 512 + rp * 8) = u0;        // hi=0 half
    *(u32x4*)(astage + kc * 512 + 256 + rp * 8) = u1;  // hi=1 half
  }
  __syncthreads();

  const int lo = hi * 256 + il * 8;
  bf16x8 af[8];
  #pragma unroll
  for (int ks = 0; ks < 8; ++ks)
    af[ks] = *(const bf16x8*)(astage + ks * 512 + lo);

  const uint16_t* WB = WTf + (size_t)(by * 16 + w * 4) * 4096;
  f32x16 acc0 = {}, acc1 = {}, acc2 = {}, acc3 = {};
  #pragma unroll
  for (int ks = 0; ks < 8; ++ks) {
    bf16x8 b0 = *(const bf16x8*)(WB + 0 * 4096 + ks * 512 + lo);
    bf16x8 b1 = *(const bf16x8*)(WB + 1 * 4096 + ks * 512 + lo);
    bf16x8 b2 = *(const bf16x8*)(WB + 2 * 4096 + ks * 512 + lo);
    bf16x8 b3 = *(const bf16x8*)(WB + 3 * 4096 + ks * 512 + lo);
    acc0 = __builtin_amdgcn_mfma_f32_32x32x16_bf16(af[ks], b0, acc0, 0, 0, 0);
    acc1 = __builtin_amdgcn_mfma_f32_32x32x16_bf16(af[ks], b1, acc1, 0, 0, 0);
    acc2 = __builtin_amdgcn_mfma_f32_32x32x16_bf16(af[ks], b2, acc2, 0, 0, 0);
    acc3 = __builtin_amdgcn_mfma_f32_32x32x16_bf16(af[ks], b3, acc3, 0, 0, 0);
  }

  // ---- stage into LDS in destination layout (local col lc) ----
  #pragma unroll
  for (int nt = 0; nt < 4; ++nt) {
    const f32x16 acc = (nt == 0) ? acc0 : (nt == 1) ? acc1 : (nt == 2) ? acc2 : acc3;
    const int lc = w * 128 + nt * 32 + il;
    const float bval = bias[by * 512 + lc];
    int cm;
    if (!vlayout) {
      const int c = (lc >> 3) & 1;
      cm = (c * 256 + (lc >> 4) * 8 + (lc & 7)) ^ (c << 4);
    } else {
      cm = ((lc >> 7) & 3) * 128 + (lc & 15) * 8 + ((lc >> 4) & 7);
    }
    #pragma unroll
    for (int r = 0; r < 16; r += 2) {
      const int rr0 = crow4(r, hi);              // r even: rr1 = rr0+1
      const uint32_t pk = cvt_pk_bf16((acc[r] + bval) * cs, (acc[r + 1] + bval) * cs);
      tile[rr0 * 512 + cm] = (uint16_t)pk;
      tile[(rr0 + 1) * 512 + cm] = (uint16_t)(pk >> 16);
    }
  }
  __syncthreads();

  // ---- coalesced store: 2048 16B-units, 8 per thread ----
  #pragma unroll
  for (int kk2 = 0; kk2 < 8; ++kk2) {
    const int u = t + kk2 * 256;
    const int rr = u >> 6, qq = u & 63;
    int toff;
    size_t gaddr;
    const size_t n = rowbase + rr;
    if (!vlayout) {
      toff = (qq * 8) ^ ((qq >> 5) << 4);   // undo stage swizzle
      gaddr = n * 2048 + (size_t)(qq >> 5) * 1024 + (size_t)by * 256 + (qq & 31) * 8;
    } else {
      toff = qq * 8;
      gaddr = n * 2048 + (size_t)by * 512 + (size_t)(qq >> 4) * 128 + (qq & 15) * 8;
    }
    u32x4 val = *(const u32x4*)(tile + rr * 512 + toff);
    *(u32x4*)(dst + gaddr) = val;
  }
}

// ---------------- Kernel 2: per-token attention ----------------
// 8 tokens/block (grid 1024), 4 waves/block. Unchanged from R8 (proven).
__global__ __launch_bounds__(256) void attn_kernel(
    const uint16_t* q3, const uint16_t* __restrict__ k3,
    const uint16_t* __restrict__ v3, uint16_t* out3) {
  __shared__ uint32_t xch[8192];   // 32 KB
  const int w = threadIdx.x >> 6;
  const int l = threadIdx.x & 63;
  const int il = l & 31, hi = l >> 5;
  const size_t n0 = (size_t)blockIdx.x * 8;
  const uint16_t* qb = q3 + n0 * 2048;
  const uint16_t* kb = k3 + n0 * 2048;
  const uint16_t* vb = v3 + n0 * 2048;
  uint16_t* ob = out3 + n0 * 2048;

  const int aoff = hi * 1024 + (w * 32 + il) * 8;   // k3 A-frag
  const int boff = hi * 1024 + il * 8;              // q3 B-frag (+ mi*256)
  uint32_t* xw = xch + (w * 2048 + il * 4 + hi * 2);        // writer base
  const uint32_t* xr = xch + (w * 512 + hi * 128 + il * 4); // reader base

  bf16x8 af  = *(const bf16x8*)(kb + aoff);
  bf16x8 bq0 = *(const bf16x8*)(qb + boff + 0);
  bf16x8 bq1 = *(const bf16x8*)(qb + boff + 256);
  bf16x8 bq2 = *(const bf16x8*)(qb + boff + 512);
  bf16x8 bq3 = *(const bf16x8*)(qb + boff + 768);

  #pragma unroll 1
  for (int tt = 0; tt < 8; ++tt) {
    // ---- V A-frags issued FIRST: latency covered by QK+softmax+pack ----
    const uint16_t* vt = vb + tt * 2048 + (il & 15) * 8;
    bf16x8 vf0 = *(const bf16x8*)(vt + (0 + hi) * 128);
    bf16x8 vf1 = *(const bf16x8*)(vt + (2 + hi) * 128);
    bf16x8 vf2 = *(const bf16x8*)(vt + (4 + hi) * 128);
    bf16x8 vf3 = *(const bf16x8*)(vt + (6 + hi) * 128);
    bf16x8 vf4 = *(const bf16x8*)(vt + (8 + hi) * 128);
    bf16x8 vf5 = *(const bf16x8*)(vt + (10 + hi) * 128);
    bf16x8 vf6 = *(const bf16x8*)(vt + (12 + hi) * 128);
    bf16x8 vf7 = *(const bf16x8*)(vt + (14 + hi) * 128);
    // ---- S^T strip: d[mi] = k_strip · q_tile(mi) ----
    f32x16 d0 = {}, d1 = {}, d2 = {}, d3 = {};
    d0 = __builtin_amdgcn_mfma_f32_32x32x16_bf16(af, bq0, d0, 0, 0, 0);
    d1 = __builtin_amdgcn_mfma_f32_32x32x16_bf16(af, bq1, d1, 0, 0, 0);
    d2 = __builtin_amdgcn_mfma_f32_32x32x16_bf16(af, bq2, d2, 0, 0, 0);
    d3 = __builtin_amdgcn_mfma_f32_32x32x16_bf16(af, bq3, d3, 0, 0, 0);
    // ---- prefetch next token's af/bq (clamped; last iter redundant) ----
    const int tn = (tt < 7) ? tt + 1 : 7;
    bf16x8 afn = *(const bf16x8*)(kb + tn * 2048 + aoff);
    bf16x8 bn0 = *(const bf16x8*)(qb + tn * 2048 + boff + 0);
    bf16x8 bn1 = *(const bf16x8*)(qb + tn * 2048 + boff + 256);
    bf16x8 bn2 = *(const bf16x8*)(qb + tn * 2048 + boff + 512);
    bf16x8 bn3 = *(const bf16x8*)(qb + tn * 2048 + boff + 768);
    // ---- softmax over i (row j = 32w + crow4(r,hi)); scale folded in q3 ----
    #pragma unroll
    for (int r = 0; r < 16; ++r) {
      float e0 = v_exp(d0[r]), e1 = v_exp(d1[r]);
      float e2 = v_exp(d2[r]), e3 = v_exp(d3[r]);
      float s = (e0 + e1) + (e2 + e3);
      s = dpp_add<0xB1>(s);    // quad_perm xor1
      s = dpp_add<0x4E>(s);    // quad_perm xor2
      s = dpp_add<0x124>(s);   // row_ror:4
      s = dpp_add<0x128>(s);   // row_ror:8  -> 16-lane row sum
      s += __builtin_bit_cast(float,
             __builtin_amdgcn_ds_swizzle(__builtin_bit_cast(int, s), 0x401F));
      const float rs = __builtin_amdgcn_rcpf(s);
      d0[r] = e0 * rs; d1[r] = e1 * rs; d2[r] = e2 * rs; d3[r] = e3 * rs;
    }
    // ---- pack P -> B-frag dword pairs, write to LDS (all u32-typed) ----
    #define PACK_WRITE(dm, mi_) do {                                           \
      u32x2 q01 = { cvt_pk_bf16(dm[0],  dm[1]),  cvt_pk_bf16(dm[2],  dm[3])  };\
      u32x2 q23 = { cvt_pk_bf16(dm[4],  dm[5]),  cvt_pk_bf16(dm[6],  dm[7])  };\
      u32x2 q45 = { cvt_pk_bf16(dm[8],  dm[9]),  cvt_pk_bf16(dm[10], dm[11]) };\
      u32x2 q67 = { cvt_pk_bf16(dm[12], dm[13]), cvt_pk_bf16(dm[14], dm[15]) };\
      uint32_t* wp_ = xw + (mi_) * 512;                                        \
      *(u32x2*)(wp_ + 0)   = q01;                                              \
      *(u32x2*)(wp_ + 128) = q23;                                              \
      *(u32x2*)(wp_ + 256) = q45;                                              \
      *(u32x2*)(wp_ + 384) = q67;                                              \
    } while (0)
    PACK_WRITE(d0, 0); PACK_WRITE(d1, 1); PACK_WRITE(d2, 2); PACK_WRITE(d3, 3);
    #undef PACK_WRITE
    __syncthreads();
    // ---- O^T = V · P : 8 MFMAs (strip ks>>1, half ks&1) ----
    f32x16 ot = {};
    u32x4 pf;
    pf = *(const u32x4*)(xr + 0 * 2048 + 0 * 256);
    ot = __builtin_amdgcn_mfma_f32_32x32x16_bf16(vf0, __builtin_bit_cast(bf16x8, pf), ot, 0, 0, 0);
    pf = *(const u32x4*)(xr + 0 * 2048 + 1 * 256);
    ot = __builtin_amdgcn_mfma_f32_32x32x16_bf16(vf1, __builtin_bit_cast(bf16x8, pf), ot, 0, 0, 0);
    pf = *(const u32x4*)(xr + 1 * 2048 + 0 * 256);
    ot = __builtin_amdgcn_mfma_f32_32x32x16_bf16(vf2, __builtin_bit_cast(bf16x8, pf), ot, 0, 0, 0);
    pf = *(const u32x4*)(xr + 1 * 2048 + 1 * 256);
    ot = __builtin_amdgcn_mfma_f32_32x32x16_bf16(vf3, __builtin_bit_cast(bf16x8, pf), ot, 0, 0, 0);
    pf = *(const u32x4*)(xr + 2 * 2048 + 0 * 256);
    ot = __builtin_amdgcn_mfma_f32_32x32x16_bf16(vf4, __builtin_bit_cast(bf16x8, pf), ot, 0, 0, 0);
    pf = *(const u32x4*)(xr + 2 * 2048 + 1 * 256);
    ot = __builtin_amdgcn_mfma_f32_32x32x16_bf16(vf5, __builtin_bit_cast(bf16x8, pf), ot, 0, 0, 0);
    pf = *(const u32x4*)(xr + 3 * 2048 + 0 * 256);
    ot = __builtin_amdgcn_mfma_f32_32x32x16_bf16(vf6, __builtin_bit_cast(bf16x8, pf), ot, 0, 0, 0);
    pf = *(const u32x4*)(xr + 3 * 2048 + 1 * 256);
    ot = __builtin_amdgcn_mfma_f32_32x32x16_bf16(vf7, __builtin_bit_cast(bf16x8, pf), ot, 0, 0, 0);
    // ---- store: lane holds col i = 32w+il, rows h = crow4(r,hi) (r 0..7) ----
    uint16_t* op = ob + tt * 2048 + (size_t)(w * 32 + il) * 16;
    *(uint32_t*)(op + 4 * hi + 0)  = cvt_pk_bf16(ot[0], ot[1]);   // h = 4hi, 4hi+1
    *(uint32_t*)(op + 4 * hi + 2)  = cvt_pk_bf16(ot[2], ot[3]);   // h = 4hi+2,3
    *(uint32_t*)(op + 4 * hi + 8)  = cvt_pk_bf16(ot[4], ot[5]);   // h = 8+4hi,+1
    *(uint32_t*)(op + 4 * hi + 10) = cvt_pk_bf16(ot[6], ot[7]);   // h = 8+4hi+2,3
    __syncthreads();   // protect LDS reuse next token
    af = afn; bq0 = bn0; bq1 = bn1; bq2 = bn2; bq3 = bn3;
  }
}

// ---------------- Kernel 3: output projection ----------------
// out = out3[8192x2048](bf16) @ Wo + bo, f32 out.
// 4 K-phases of 512: stage A panel 32x512 into LDS [32][520]; each thread
// covers its full 32-elem chunk with FOUR 16B copies (R9/R10 bug: only 2 of 4
// issued -> half the panel was stale). B reads keep R8-proven WoT[col][k];
// per phase, wave ksv covers k = kw*512 + ksv*256 + s*16 + hi*8 (disjoint,
// union complete) -> part[] ksv-pair reduce epilogue unchanged from R8.
__global__ __launch_bounds__(512) void outproj_kernel(
    const uint16_t* __restrict__ out3, const uint16_t* __restrict__ WoT,
    const float* __restrict__ bo, float* __restrict__ out) {
  __shared__ uint16_t astage[32 * 520];   // ~33 KB (row stride 520: 16B-aligned)
  __shared__ float part[4][32][32];       // 16 KB
  const int t = threadIdx.x;
  const int w = t >> 6;
  const int l = t & 63;
  const int il = l & 31, hi = l >> 5;
  const int nt = w >> 1, ksv = w & 1;
  const int rowbase = blockIdx.x * 32;
  const int srow = t >> 4, scol = (t & 15) * 32;
  const uint16_t* arow = out3 + (size_t)(rowbase + srow) * DH;
  const uint16_t* ab = astage + il * 520 + ksv * 256 + hi * 8;
  const uint16_t* brow = WoT + (size_t)(nt * 32 + il) * DH + ksv * 256 + hi * 8;
  f32x16 acc = {};
  #pragma unroll 1
  for (int kw = 0; kw < 4; ++kw) {
    __syncthreads();                      // previous phase's readers done
    #pragma unroll
    for (int c4 = 0; c4 < 4; ++c4) {      // FULL 32-elem coverage (4 x 8 elems)
      *(u32x4*)(astage + srow * 520 + scol + c4 * 8) =
          *(const u32x4*)(arow + kw * 512 + scol + c4 * 8);
    }
    __syncthreads();
    const uint16_t* bk = brow + kw * 512;
    #pragma unroll
    for (int s = 0; s < 16; ++s) {
      bf16x8 afr = *(const bf16x8*)(ab + s * 16);
      bf16x8 bfr = *(const bf16x8*)(bk + s * 16);
      acc = __builtin_amdgcn_mfma_f32_32x32x16_bf16(afr, bfr, acc, 0, 0, 0);
    }
  }
  __syncthreads();
  if (ksv == 1) {
    #pragma unroll
    for (int r = 0; r < 16; ++r) part[nt][crow4(r, hi)][il] = acc[r];
  }
  __syncthreads();
  if (ksv == 0) {
    const int col = nt * 32 + il;
    const float bval = bo[col];
    #pragma unroll
    for (int r = 0; r < 16; ++r) {
      const int rr = crow4(r, hi);
      out[(size_t)(rowbase + rr) * DDIM + col] = acc[r] + part[nt][rr][il] + bval;
    }
  }
}

extern "C" void kernel_launch(void* const* d_in, const int* in_sizes, int n_in,
                              void* d_out, int out_size, void* d_ws, size_t ws_size,
                              hipStream_t stream) {
  (void)in_sizes; (void)n_in; (void)out_size; (void)ws_size;
  const float* q  = (const float*)d_in[0];
  const float* k  = (const float*)d_in[1];
  const float* v  = (const float*)d_in[2];
  const float* Wq = (const float*)d_in[3];
  const float* bq = (const float*)d_in[4];
  const float* Wk = (const float*)d_in[5];
  const float* bk = (const float*)d_in[6];
  const float* Wv = (const float*)d_in[7];
  const float* bv = (const float*)d_in[8];
  const float* Wo = (const float*)d_in[9];
  const float* bo = (const float*)d_in[10];
  float* out = (float*)d_out;

  char* ws = (char*)d_ws;
  const size_t MB = 1024ull * 1024ull;
  uint16_t* q3  = (uint16_t*)(ws);             // 32MB; becomes out3
  uint16_t* k3  = (uint16_t*)(ws + 32 * MB);
  uint16_t* v3  = (uint16_t*)(ws + 64 * MB);
  uint16_t* WqT = (uint16_t*)(ws + 96 * MB);   // 512KB each
  uint16_t* WkT = WqT + (size_t)DH * 128;
  uint16_t* WvT = WkT + (size_t)DH * 128;
  uint16_t* WoT = WvT + (size_t)DH * 128;

  prep_weights<<<dim3(8, 4), 256, 0, stream>>>(Wq, Wk, Wv, Wo, WqT, WkT, WvT, WoT);
  proj_kernel<<<dim3(256, 4, 3), 256, 0, stream>>>(q, k, v, WqT, WkT, WvT,
                                                   bq, bk, bv, q3, k3, v3);
  attn_kernel<<<dim3(1024), 256, 0, stream>>>(q3, k3, v3, q3);
  outproj_kernel<<<dim3(256), 512, 0, stream>>>(q3, WoT, bo, out);
}